// Round 2
// baseline (203.509 us; speedup 1.0000x reference)
//
#include <hip/hip_runtime.h>

// WaveletFeatureAugmentation: out[row] = concat(x[row] (4096 f32),
//   Linear14x14(wavedec_db4_approx_9levels(x[row]))).
// One block per row. Each DWT level keeps its signal deinterleaved in LDS as
// even/odd arrays so the interior stencil is a branch-free, lane-contiguous
// float4 read (conflict-free ds_read_b128) + 8 FMA per output.

#define ROWS 16384          // 32*512
#define N0   4096
#define OUTW 4110           // 4096 + 14

// db4 dec_lo taps
#define D0 -0.010597401784997278f
#define D1  0.032883011666982945f
#define D2  0.030841381835986965f
#define D3 -0.18703481171888114f
#define D4 -0.02798376941698385f
#define D5  0.6308807679295904f
#define D6  0.7148465705525415f
#define D7  0.23037781330885523f
// y[i] = sum_j a[2i-6+j]*crev[j], crev[j] = d[7-j]
// even taps CE[m] = d[7-2m], odd taps CO[m] = d[6-2m]
#define CE0 D7
#define CE1 D5
#define CE2 D3
#define CE3 D1
#define CO0 D6
#define CO1 D4
#define CO2 D2
#define CO3 D0

// One DWT-lo level, deinterleaved in (ein,oin) -> deinterleaved out (eout,oout).
// a[t] == (t&1) ? oin[t>>1] : ein[t>>1]; input length n.
__device__ __forceinline__ void dwt_level(const float* __restrict__ ein,
                                          const float* __restrict__ oin,
                                          float* __restrict__ eout,
                                          float* __restrict__ oout,
                                          int n, int tid, int nthreads)
{
    const float crev[8] = {D7, D6, D5, D4, D3, D2, D1, D0};
    const int nout = (n + 7) >> 1;
    const int nchunks = (nout + 3) >> 2;
    const int clast = (n - 8) >> 3;     // interior chunks: c in [1, clast]
    for (int c = tid; c < nchunks; c += nthreads) {
        if (c >= 1 && c <= clast) {
            // windows e[4c-4 .. 4c+3], o[4c-4 .. 4c+3] (we[0]/wo[0] unused)
            const float4 e0 = *reinterpret_cast<const float4*>(ein + 4 * c - 4);
            const float4 e1 = *reinterpret_cast<const float4*>(ein + 4 * c);
            const float4 o0 = *reinterpret_cast<const float4*>(oin + 4 * c - 4);
            const float4 o1 = *reinterpret_cast<const float4*>(oin + 4 * c);
            const float we[8] = {e0.x, e0.y, e0.z, e0.w, e1.x, e1.y, e1.z, e1.w};
            const float wo[8] = {o0.x, o0.y, o0.z, o0.w, o1.x, o1.y, o1.z, o1.w};
            float y[4];
            #pragma unroll
            for (int j = 0; j < 4; ++j) {
                float acc =      we[j + 1] * CE0;
                acc = fmaf(we[j + 2], CE1, acc);
                acc = fmaf(we[j + 3], CE2, acc);
                acc = fmaf(we[j + 4], CE3, acc);
                acc = fmaf(wo[j + 1], CO0, acc);
                acc = fmaf(wo[j + 2], CO1, acc);
                acc = fmaf(wo[j + 3], CO2, acc);
                acc = fmaf(wo[j + 4], CO3, acc);
                y[j] = acc;
            }
            // outputs go out already deinterleaved for the next level
            *reinterpret_cast<float2*>(eout + 2 * c) = make_float2(y[0], y[2]);
            *reinterpret_cast<float2*>(oout + 2 * c) = make_float2(y[1], y[3]);
        } else {
            // boundary / partial chunk: generic pywt 'symmetric' extension
            #pragma unroll
            for (int j = 0; j < 4; ++j) {
                const int i = 4 * c + j;
                if (i < nout) {
                    float acc = 0.f;
                    #pragma unroll
                    for (int jj = 0; jj < 8; ++jj) {
                        int t = 2 * i - 6 + jj;
                        int tt = (t < 0) ? (-1 - t) : ((t >= n) ? (2 * n - 1 - t) : t);
                        float a = (tt & 1) ? oin[tt >> 1] : ein[tt >> 1];
                        acc = fmaf(a, crev[jj], acc);
                    }
                    if (i & 1) oout[i >> 1] = acc;
                    else       eout[i >> 1] = acc;
                }
            }
        }
    }
}

#define WAVE_LDS_FENCE() do {                                   \
    asm volatile("s_waitcnt lgkmcnt(0)" ::: "memory");          \
    __builtin_amdgcn_sched_barrier(0);                          \
} while (0)

__global__ __launch_bounds__(256) void wavelet_aug_kernel(
    const float* __restrict__ x, const float* __restrict__ W,
    const float* __restrict__ b, float* __restrict__ out)
{
    __shared__ __align__(16) float eA[2048];
    __shared__ __align__(16) float oA[2048];
    __shared__ __align__(16) float eB[1026];
    __shared__ __align__(16) float oB[1026];

    const int row = blockIdx.x;
    const int tid = threadIdx.x;
    const float* xr   = x   + (size_t)row * N0;
    float*       outr = out + (size_t)row * OUTW;

    // Load row (float4), pass through to out (float2 stores; out row base is
    // only 8B-aligned), and deinterleave into eA/oA.
    const float4* x4 = reinterpret_cast<const float4*>(xr);
    float2* out2 = reinterpret_cast<float2*>(outr);
    for (int i = tid; i < N0 / 4; i += 256) {
        const float4 v = x4[i];
        out2[2 * i]     = make_float2(v.x, v.y);
        out2[2 * i + 1] = make_float2(v.z, v.w);
        *reinterpret_cast<float2*>(eA + 2 * i) = make_float2(v.x, v.z);
        *reinterpret_cast<float2*>(oA + 2 * i) = make_float2(v.y, v.w);
    }
    __syncthreads();

    // Block-wide levels (input lengths 4096, 2051, 1029, 518)
    dwt_level(eA, oA, eB, oB, 4096, tid, 256); __syncthreads();
    dwt_level(eB, oB, eA, oA, 2051, tid, 256); __syncthreads();
    dwt_level(eA, oA, eB, oB, 1029, tid, 256); __syncthreads();
    dwt_level(eB, oB, eA, oA,  518, tid, 256); __syncthreads();

    // Tail levels fit one wave: waves 1..3 retire, wave 0 finishes.
    if (tid >= 64) return;

    dwt_level(eA, oA, eB, oB, 262, tid, 64); WAVE_LDS_FENCE();
    dwt_level(eB, oB, eA, oA, 134, tid, 64); WAVE_LDS_FENCE();
    dwt_level(eA, oA, eB, oB,  70, tid, 64); WAVE_LDS_FENCE();
    dwt_level(eB, oB, eA, oA,  38, tid, 64); WAVE_LDS_FENCE();
    dwt_level(eA, oA, eB, oB,  22, tid, 64); WAVE_LDS_FENCE();
    // 14 approx coefficients now in eB[0..6] / oB[0..6]

    // aug[o] = b[o] + sum_f approx[f] * W[o][f]
    if (tid < 14) {
        float acc = b[tid];
        #pragma unroll
        for (int f = 0; f < 14; ++f) {
            const float a = (f & 1) ? oB[f >> 1] : eB[f >> 1];
            acc = fmaf(a, W[tid * 14 + f], acc);
        }
        outr[N0 + tid] = acc;
    }
}

extern "C" void kernel_launch(void* const* d_in, const int* in_sizes, int n_in,
                              void* d_out, int out_size, void* d_ws, size_t ws_size,
                              hipStream_t stream) {
    const float* x = (const float*)d_in[0];   // [32,512,4096]
    const float* W = (const float*)d_in[1];   // [14,14]
    const float* b = (const float*)d_in[2];   // [14]
    float* out = (float*)d_out;               // [32,512,4110]
    wavelet_aug_kernel<<<ROWS, 256, 0, stream>>>(x, W, b, out);
}